// Round 6
// baseline (201.829 us; speedup 1.0000x reference)
//
#include <hip/hip_runtime.h>
#include <hip/hip_bf16.h>
#include <cstddef>
#include <cstdint>

// GINConvFFT round 6: 3 launches, BK=64 fat K-loops, grid-barrier fused BN.
//   prep:    xb=bf16(x); MallC even slices=(1+eps)I+A_s; MT; Wt; zero counters
//   zgemmsq: blocks 0-255: Zcat[(b*64+o)][k*512+m] = Wt[k*64+o][:].xb[b*512+m][:]
//            blocks 256-287: MallC odd slices = M_s^2  (both 128x128, BK=64)
//   ysumbn:  Yh[ks] = partial (k-half) of MallC . Zcat^T; grid barrier;
//            BN partials; grid barrier; stats+normalize+relu+w2+b2 -> out
#define B_   32
#define N_   512
#define D_   768
#define OUT_ 64
#define R_   (B_ * N_)

typedef unsigned short u16;
typedef __bf16 bf16x8 __attribute__((ext_vector_type(8)));
typedef float  f32x4  __attribute__((ext_vector_type(4)));
typedef unsigned short u16x8 __attribute__((ext_vector_type(8)));

__device__ __forceinline__ u16 f2bf(float f) {
    __hip_bfloat16 h = __float2bfloat16(f);
    return __builtin_bit_cast(u16, h);
}

__device__ __forceinline__ f32x4 mfma16(u16x8 a, u16x8 b, f32x4 c) {
    return __builtin_amdgcn_mfma_f32_16x16x32_bf16(
        __builtin_bit_cast(bf16x8, a), __builtin_bit_cast(bf16x8, b), c, 0, 0, 0);
}

// async global->LDS, 16B/lane; LDS dest = wave-uniform base + lane*16
__device__ __forceinline__ void gl2lds16(const void* g, void* l) {
    __builtin_amdgcn_global_load_lds(
        (const __attribute__((address_space(1))) unsigned int*)g,
        (__attribute__((address_space(3))) unsigned int*)l, 16, 0, 0);
}

// grid barrier: all 256 blocks resident (256 blocks on 256 CUs). cnt zeroed by prep.
__device__ __forceinline__ void gridbar(int* cnt, int nblk) {
    __syncthreads();
    if (threadIdx.x == 0) {
        __threadfence();   // agent scope: flush stores for cross-XCD visibility
        __hip_atomic_fetch_add(cnt, 1, __ATOMIC_ACQ_REL, __HIP_MEMORY_SCOPE_AGENT);
        while (__hip_atomic_load(cnt, __ATOMIC_ACQUIRE, __HIP_MEMORY_SCOPE_AGENT) < nblk)
            __builtin_amdgcn_s_sleep(2);
    }
    __syncthreads();
}

// ---------------------------------------------------------------------------
// prep: [0,6144) cast x | [6144,6656) M,MT | [6656,7424) Wt. Block 0 zeroes cnt.
// ---------------------------------------------------------------------------
__global__ __launch_bounds__(256) void prep(
    const float* __restrict__ x, const float* __restrict__ support,
    const float* __restrict__ weight, const float* __restrict__ epsp,
    u16* __restrict__ xb, u16* __restrict__ MallC, u16* __restrict__ MT,
    u16* __restrict__ Wt, int* __restrict__ cnt)
{
    const int blk = blockIdx.x, tid = threadIdx.x;
    __shared__ float t[32][33];
    if (blk < 6144) {
        if (blk == 0 && tid < 2) cnt[tid] = 0;
        int i = (blk * 256 + tid) * 8;
        f32x4 a = *(const f32x4*)(x + i);
        f32x4 b = *(const f32x4*)(x + i + 4);
        u16x8 o;
#pragma unroll
        for (int j = 0; j < 4; ++j) { o[j] = f2bf(a[j]); o[4 + j] = f2bf(b[j]); }
        *(u16x8*)(xb + i) = o;
    } else if (blk < 6656) {
        int local = blk - 6144;
        int s = local >> 8, rem = local & 255;
        int n0 = (rem >> 4) * 32, m0 = (rem & 15) * 32;
        const float f = 1.0f + epsp[0];
        const float* S = support + (size_t)s * 262144;
#pragma unroll
        for (int p = 0; p < 4; ++p) {
            int nl = p * 8 + (tid >> 5), ml = tid & 31;
            float v = S[(size_t)(n0 + nl) * 512 + m0 + ml];
            if (n0 + nl == m0 + ml) v += f;
            MallC[(size_t)(n0 + nl) * 2048 + s * 1024 + m0 + ml] = f2bf(v);
            t[nl][ml] = v;
        }
        __syncthreads();
#pragma unroll
        for (int p = 0; p < 4; ++p) {
            int ml = p * 8 + (tid >> 5), nl = tid & 31;
            MT[(size_t)s * 262144 + (size_t)(m0 + ml) * 512 + n0 + nl] = f2bf(t[nl][ml]);
        }
    } else {
        int idx = (blk - 6656) * 256 + tid;
        int k = idx / 49152, rem = idx % 49152;
        int o = rem / 768, d = rem % 768;
        int l = d >> 6, hh = d & 63;
        Wt[idx] = f2bf(weight[((size_t)l * 256 + hh * 4 + k) * 64 + o]);
    }
}

// ---------------------------------------------------------------------------
// zgemmsq: 128x128 C=A.B^T tiles, BK=64 (2 panels/iter, 32 MFMA+8 loads per
// wave per barrier pair). Blocks 0-255: zgemm (K=768). 256-287: msq (K=512).
// ---------------------------------------------------------------------------
__global__ __launch_bounds__(256) void zgemmsq(
    const u16* __restrict__ Wt, const u16* __restrict__ xb,
    const u16* __restrict__ MallC_in, const u16* __restrict__ MT,
    u16* __restrict__ Z, u16* __restrict__ MallC_out)
{
    __shared__ __align__(16) char smem[36864];   // staging 32KB | repack 36KB
    u16* St = (u16*)smem;
    const int tid = threadIdx.x, lane = tid & 63, wid = tid >> 6;
    const int wr = wid >> 1, wc = wid & 1;
    const int lrow = lane & 15, lk = (lane >> 4) * 8;
    const int bid = blockIdx.x;

    const u16 *Ab, *Bb;
    int strA, strB, kIters, i0, j0, s = 0;
    bool ismsq;
    if (bid < 256) {
        ismsq = false;
        i0 = (bid >> 7) * 128; j0 = (bid & 127) * 128;
        Ab = Wt; strA = 768; Bb = xb; strB = 768; kIters = 12;
    } else {
        ismsq = true;
        int lb = bid - 256;
        s = lb >> 4; int rem = lb & 15;
        i0 = (rem >> 2) * 128; j0 = (rem & 3) * 128;
        Ab = MallC_in + s * 1024; strA = 2048;
        Bb = MT + (size_t)s * 262144; strB = 512; kIters = 8;
    }

    const u16* gsrc[8]; u16* ldst[8];
#pragma unroll
    for (int t = 0; t < 8; ++t) {
        int idx = wid * 8 + t;
        int pan = idx >> 4, q2 = idx & 15;
        if (q2 < 8) {
            gsrc[t] = Ab + (size_t)(i0 + q2 * 16 + lrow) * strA + pan * 32 + lk;
            ldst[t] = St + pan * 8192 + q2 * 512;
        } else {
            gsrc[t] = Bb + (size_t)(j0 + (q2 - 8) * 16 + lrow) * strB + pan * 32 + lk;
            ldst[t] = St + pan * 8192 + 4096 + (q2 - 8) * 512;
        }
    }
    f32x4 acc[4][4] = {};
    for (int kk = 0; kk < kIters; ++kk) {
#pragma unroll
        for (int t = 0; t < 8; ++t) gl2lds16(gsrc[t], ldst[t]);
#pragma unroll
        for (int t = 0; t < 8; ++t) gsrc[t] += 64;
        __syncthreads();
#pragma unroll
        for (int pan = 0; pan < 2; ++pan) {
            u16x8 af[4], bq[4];
#pragma unroll
            for (int f = 0; f < 4; ++f)
                af[f] = *(const u16x8*)(St + pan * 8192 + (wr * 4 + f) * 512 + lane * 8);
#pragma unroll
            for (int f = 0; f < 4; ++f)
                bq[f] = *(const u16x8*)(St + pan * 8192 + 4096 + (wc * 4 + f) * 512 + lane * 8);
#pragma unroll
            for (int fi = 0; fi < 4; ++fi)
#pragma unroll
                for (int fj = 0; fj < 4; ++fj)
                    acc[fi][fj] = mfma16(af[fi], bq[fj], acc[fi][fj]);
        }
        __syncthreads();
    }
    const int q = lane >> 4;
    if (!ismsq) {
        // repack wave's 64x64 (rows=o, cols=m) then vector stores to Zcat
        u16* Rw = (u16*)smem + wid * 4608;           // 64 rows x 72 u16
#pragma unroll
        for (int fi = 0; fi < 4; ++fi)
#pragma unroll
            for (int fj = 0; fj < 4; ++fj)
#pragma unroll
                for (int r = 0; r < 4; ++r)
                    Rw[(fi * 16 + q * 4 + r) * 72 + fj * 16 + lrow] = f2bf(acc[fi][fj][r]);
        __syncthreads();
        const int k = (i0 >> 6) + wr;
        const int b = j0 >> 9;
        const int m0 = (j0 & 511) + wc * 64;
#pragma unroll
        for (int p = 0; p < 8; ++p) {
            int row = p * 8 + (lane >> 3);           // = o
            int cc = (lane & 7) * 8;
            u16x8 v = *(const u16x8*)(Rw + row * 72 + cc);
            *(u16x8*)(Z + (size_t)(b * 64 + row) * 2048 + k * 512 + m0 + cc) = v;
        }
    } else {
#pragma unroll
        for (int fi = 0; fi < 4; ++fi)
#pragma unroll
            for (int fj = 0; fj < 4; ++fj)
#pragma unroll
                for (int r = 0; r < 4; ++r) {
                    int n = i0 + wr * 64 + fi * 16 + q * 4 + r;
                    int c = j0 + wc * 64 + fj * 16 + lrow;
                    MallC_out[(size_t)n * 2048 + (2 * s + 1) * 512 + c] = f2bf(acc[fi][fj][r]);
                }
    }
}

// ---------------------------------------------------------------------------
// ysumbn: grid (128 r-tiles, 2 ksplit) = 256 blocks.
// Phase 1: Yh[ks][r][o] = sum_{km in half} MallC[n][km]*Z[b*64+o][km]
//          (128r x 64o, BK=64, waves 2x2 of 64r x 32o)
// barrier; Phase 2: v=Yh0+Yh1 for 64-row chunk, BN partials; barrier;
// Phase 3: stats, normalize+relu, w2 GEMM, +b2 -> out.
// ---------------------------------------------------------------------------
__global__ __launch_bounds__(256) void ysumbn(
    const u16* __restrict__ MallC, const u16* __restrict__ Z,
    float* __restrict__ Yh, float* __restrict__ part, int* __restrict__ cnt,
    const float* __restrict__ gamma, const float* __restrict__ beta,
    const float* __restrict__ w2, const float* __restrict__ b2,
    float* __restrict__ out)
{
    __shared__ __align__(16) char smem[36864];
    u16* St = (u16*)smem;                         // staging: 2 panels x 6144 u16
    float* ys    = (float*)smem;                  // [64 o][68] rows
    float* w2s   = (float*)(smem + 17408);        // [64][65]
    float* red   = (float*)(smem + 34048);        // [4][64]
    float* red2  = (float*)(smem + 35072);        // [4][64]
    float* stats = (float*)(smem + 36096);        // [128]
    const int tid = threadIdx.x, lane = tid & 63, wid = tid >> 6;
    const int wr = wid >> 1, wc = wid & 1;
    const int lrow = lane & 15, lk = (lane >> 4) * 8;
    const int r0 = blockIdx.x * 128, ks = blockIdx.y;
    const int b = blockIdx.x >> 2, n0 = r0 & 511;
    const size_t km0 = (size_t)ks * 1024;

    const u16* gsrc[6]; u16* ldst[6];
#pragma unroll
    for (int t = 0; t < 6; ++t) {
        int idx = wid * 6 + t;
        int pan = idx / 12, q2 = idx % 12;
        if (q2 < 8) {
            gsrc[t] = MallC + (size_t)(n0 + q2 * 16 + lrow) * 2048 + km0 + pan * 32 + lk;
            ldst[t] = St + pan * 6144 + q2 * 512;
        } else {
            gsrc[t] = Z + (size_t)(b * 64 + (q2 - 8) * 16 + lrow) * 2048 + km0 + pan * 32 + lk;
            ldst[t] = St + pan * 6144 + 4096 + (q2 - 8) * 512;
        }
    }
    f32x4 acc[4][2] = {};
    for (int kk = 0; kk < 16; ++kk) {
#pragma unroll
        for (int t = 0; t < 6; ++t) gl2lds16(gsrc[t], ldst[t]);
#pragma unroll
        for (int t = 0; t < 6; ++t) gsrc[t] += 64;
        __syncthreads();
#pragma unroll
        for (int pan = 0; pan < 2; ++pan) {
            u16x8 af[4], bq[2];
#pragma unroll
            for (int f = 0; f < 4; ++f)
                af[f] = *(const u16x8*)(St + pan * 6144 + (wr * 4 + f) * 512 + lane * 8);
#pragma unroll
            for (int f = 0; f < 2; ++f)
                bq[f] = *(const u16x8*)(St + pan * 6144 + 4096 + (wc * 2 + f) * 512 + lane * 8);
#pragma unroll
            for (int fi = 0; fi < 4; ++fi)
#pragma unroll
                for (int fj = 0; fj < 2; ++fj)
                    acc[fi][fj] = mfma16(af[fi], bq[fj], acc[fi][fj]);
        }
        __syncthreads();
    }
    // phase-1 store: fp32 half-buffer
    const int q = lane >> 4;
    float* Yk = Yh + (size_t)ks * R_ * 64;
#pragma unroll
    for (int fi = 0; fi < 4; ++fi)
#pragma unroll
        for (int fj = 0; fj < 2; ++fj)
#pragma unroll
            for (int r = 0; r < 4; ++r) {
                int rr = r0 + wr * 64 + fi * 16 + q * 4 + r;
                int o  = wc * 32 + fj * 16 + lrow;
                Yk[(size_t)rr * 64 + o] = acc[fi][fj][r];
            }

    gridbar(cnt, 256);

    // phase 2: this block takes rows bid*64..+63; v = Yh0+Yh1; BN partials
    const int bid = blockIdx.y * 128 + blockIdx.x;
    const int rb = bid * 64;
    const int o = tid & 63, g = tid >> 6;
    {
        float s = 0.f, s2 = 0.f;
#pragma unroll
        for (int p = 0; p < 16; ++p) {
            int rl = p * 4 + g;
            size_t off = (size_t)(rb + rl) * 64 + o;
            float v = Yh[off] + Yh[(size_t)R_ * 64 + off];
            ys[o * 68 + rl] = v;
            s += v; s2 += v * v;
        }
        red[g * 64 + o] = s; red2[g * 64 + o] = s2;
    }
    // load w2 while here
#pragma unroll
    for (int i = 0; i < 16; ++i) {
        int idx = tid + i * 256;
        w2s[(idx >> 6) * 65 + (idx & 63)] = w2[idx];
    }
    __syncthreads();
    if (tid < 64) {
        float t0 = red[tid] + red[64 + tid] + red[128 + tid] + red[192 + tid];
        float t2 = red2[tid] + red2[64 + tid] + red2[128 + tid] + red2[192 + tid];
        part[bid * 128 + tid]      = t0;
        part[bid * 128 + 64 + tid] = t2;
    }

    gridbar(cnt + 1, 256);

    // phase 3a: stats (every block reduces all partials from L2)
    {
        float s = 0.f, s2 = 0.f;
        for (int p = g; p < 256; p += 4) {
            s  += part[p * 128 + o];
            s2 += part[p * 128 + 64 + o];
        }
        red[g * 64 + o] = s; red2[g * 64 + o] = s2;
    }
    __syncthreads();
    if (tid < 64) {
        float t0 = red[tid] + red[64 + tid] + red[128 + tid] + red[192 + tid];
        float t2 = red2[tid] + red2[64 + tid] + red2[128 + tid] + red2[192 + tid];
        float mean = t0 * (1.0f / R_);
        float var  = t2 * (1.0f / R_) - mean * mean;
        float rstd = rsqrtf(var + 1e-5f);
        float a = rstd * gamma[tid];
        stats[tid]      = a;                      // scale
        stats[64 + tid] = beta[tid] - mean * a;   // shift
    }
    __syncthreads();
    // phase 3b: normalize + relu in LDS
    {
        float a = stats[o], sh = stats[64 + o];
#pragma unroll
        for (int p = 0; p < 16; ++p) {
            int rl = p * 4 + g;
            float v = ys[o * 68 + rl];
            ys[o * 68 + rl] = fmaxf(fmaf(v, a, sh), 0.f);
        }
    }
    __syncthreads();
    // phase 3c: w2 GEMM + b2
    {
        const int rg = g;
        float accs[16];
        float bb = b2[o];
#pragma unroll
        for (int j = 0; j < 16; ++j) accs[j] = bb;
        for (int c = 0; c < 64; ++c) {
            float wv = w2s[o * 65 + c];
            const float* yr = ys + c * 68 + rg * 16;
            f32x4 y0 = *(const f32x4*)(yr);
            f32x4 y1 = *(const f32x4*)(yr + 4);
            f32x4 y2 = *(const f32x4*)(yr + 8);
            f32x4 y3 = *(const f32x4*)(yr + 12);
#pragma unroll
            for (int j = 0; j < 4; ++j) {
                accs[j]      = fmaf(wv, y0[j], accs[j]);
                accs[4 + j]  = fmaf(wv, y1[j], accs[4 + j]);
                accs[8 + j]  = fmaf(wv, y2[j], accs[8 + j]);
                accs[12 + j] = fmaf(wv, y3[j], accs[12 + j]);
            }
        }
#pragma unroll
        for (int j = 0; j < 16; ++j)
            out[(size_t)(rb + rg * 16 + j) * OUT_ + o] = accs[j];
    }
}

// ---------------------------------------------------------------------------
extern "C" void kernel_launch(void* const* d_in, const int* in_sizes, int n_in,
                              void* d_out, int out_size, void* d_ws, size_t ws_size,
                              hipStream_t stream)
{
    const float* x       = (const float*)d_in[0];
    const float* support = (const float*)d_in[1];
    const float* weight  = (const float*)d_in[2];
    const float* eps     = (const float*)d_in[3];
    const float* gamma   = (const float*)d_in[4];
    const float* beta    = (const float*)d_in[5];
    const float* w2      = (const float*)d_in[6];
    const float* b2      = (const float*)d_in[7];
    float* out = (float*)d_out;

    char* ws = (char*)d_ws;
    u16*   xb    = (u16*)(ws);                      // 25,165,824
    u16*   MallC = (u16*)(ws + 25165824);           //  2,097,152  [512][2048]
    u16*   MT    = (u16*)(ws + 27262976);           //  1,048,576
    u16*   Wt    = (u16*)(ws + 28311552);           //    393,216
    u16*   Z     = (u16*)(ws + 28704768);           //  8,388,608  [2048][2048]
    float* Yh    = (float*)(ws + 37093376);         //  8,388,608  (2 halves)
    float* part  = (float*)(ws + 45481984);         //    131,072
    int*   cnt   = (int*)(ws + 45613056);           //         16

    prep   <<<7424,          256, 0, stream>>>(x, support, weight, eps,
                                               xb, MallC, MT, Wt, cnt);
    zgemmsq<<<288,           256, 0, stream>>>(Wt, xb, MallC, MT, Z, MallC);
    ysumbn <<<dim3(128, 2),  256, 0, stream>>>(MallC, Z, Yh, part, cnt,
                                               gamma, beta, w2, b2, out);
}

// Round 7
// 172.738 us; speedup vs baseline: 1.1684x; 1.1684x over previous
//
#include <hip/hip_runtime.h>
#include <hip/hip_bf16.h>
#include <cstddef>
#include <cstdint>

// GINConvFFT round 7: no grid barrier, 2 blocks/CU GEMMs, fused fp32->bf16
// conversion inside zgemm (x never pre-cast).
//   prep2:      MallC even slices=(1+eps)I+A_s; MT; Wt          (1280 blocks)
//   zgemm_fused blocks 0-511:  Z[(b*64+o)][k*512+m] = Wt[k*64+o][:] . x[b*512+m][:]
//               blocks 512-543: MallC odd slices = M_s^2        (544 blocks)
//   ysum:       Yh[ks][r][o] = partial (k-half) MallC . Z^T     (512 blocks)
//   bn_part/bn_final/bn_out: BN stats over Yh0+Yh1, normalize+relu+w2+b2.
#define B_   32
#define N_   512
#define D_   768
#define OUT_ 64
#define R_   (B_ * N_)

typedef unsigned short u16;
typedef __bf16 bf16x8 __attribute__((ext_vector_type(8)));
typedef float  f32x4  __attribute__((ext_vector_type(4)));
typedef unsigned short u16x8 __attribute__((ext_vector_type(8)));

__device__ __forceinline__ u16 f2bf(float f) {
    __hip_bfloat16 h = __float2bfloat16(f);
    return __builtin_bit_cast(u16, h);
}

__device__ __forceinline__ f32x4 mfma16(u16x8 a, u16x8 b, f32x4 c) {
    return __builtin_amdgcn_mfma_f32_16x16x32_bf16(
        __builtin_bit_cast(bf16x8, a), __builtin_bit_cast(bf16x8, b), c, 0, 0, 0);
}

// async global->LDS, 16B/lane; LDS dest = wave-uniform base + lane*16
__device__ __forceinline__ void gl2lds16(const void* g, void* l) {
    __builtin_amdgcn_global_load_lds(
        (const __attribute__((address_space(1))) unsigned int*)g,
        (__attribute__((address_space(3))) unsigned int*)l, 16, 0, 0);
}

// ---------------------------------------------------------------------------
// prep2: [0,512) build M (even MallC col slices) + MT | [512,1280) build Wt
// ---------------------------------------------------------------------------
__global__ __launch_bounds__(256) void prep2(
    const float* __restrict__ support, const float* __restrict__ weight,
    const float* __restrict__ epsp,
    u16* __restrict__ MallC, u16* __restrict__ MT, u16* __restrict__ Wt)
{
    const int blk = blockIdx.x, tid = threadIdx.x;
    __shared__ float t[32][33];
    if (blk < 512) {
        int s = blk >> 8, rem = blk & 255;
        int n0 = (rem >> 4) * 32, m0 = (rem & 15) * 32;
        const float f = 1.0f + epsp[0];
        const float* S = support + (size_t)s * 262144;
#pragma unroll
        for (int p = 0; p < 4; ++p) {
            int nl = p * 8 + (tid >> 5), ml = tid & 31;
            float v = S[(size_t)(n0 + nl) * 512 + m0 + ml];
            if (n0 + nl == m0 + ml) v += f;
            MallC[(size_t)(n0 + nl) * 2048 + s * 1024 + m0 + ml] = f2bf(v);
            t[nl][ml] = v;
        }
        __syncthreads();
#pragma unroll
        for (int p = 0; p < 4; ++p) {
            int ml = p * 8 + (tid >> 5), nl = tid & 31;
            MT[(size_t)s * 262144 + (size_t)(m0 + ml) * 512 + n0 + nl] = f2bf(t[nl][ml]);
        }
    } else {
        int idx = (blk - 512) * 256 + tid;          // 4*64*768 = 196608
        int k = idx / 49152, rem = idx % 49152;
        int o = rem / 768, d = rem % 768;
        int l = d >> 6, hh = d & 63;
        Wt[idx] = f2bf(weight[((size_t)l * 256 + hh * 4 + k) * 64 + o]);
    }
}

// ---------------------------------------------------------------------------
// zgemm_fused:
//  blocks 0-511: bid -> rt = bid>>1 (m-tile of 64), y = bid&1 (Wt row half).
//    A = Wt rows [y*128, y*128+128) (bf16, gl2lds staged)
//    B = x rows [rt*64, rt*64+64) fp32, converted in-kernel to bf16 LDS
//    C 128x64, K=768, BK=64. Waves 2x2: each 64(A-rows) x 32(m).
//  blocks 512-543: msq 128x128, K=512, BK=64 (round-6 structure).
// ---------------------------------------------------------------------------
__global__ __launch_bounds__(256) void zgemm_fused(
    const u16* __restrict__ Wt, const float* __restrict__ x,
    const u16* __restrict__ MallC_in, const u16* __restrict__ MT,
    u16* __restrict__ Z, u16* __restrict__ MallC_out)
{
    __shared__ __align__(16) char smem[32768];
    const int tid = threadIdx.x, lane = tid & 63, wid = tid >> 6;
    const int wr = wid >> 1, wc = wid & 1;
    const int lrow = lane & 15, lk = (lane >> 4) * 8;
    const int q = lane >> 4;
    const int bid = blockIdx.x;

    if (bid < 512) {
        u16* As = (u16*)smem;                 // 2 panels x 8 subtiles x 512 u16
        u16* Bs = (u16*)(smem + 16384);       // 2 panels x 4 subtiles x 512 u16
        const int rt = bid >> 1, y = bid & 1;
        const int j0 = rt * 64;

        // A staging: 16 gl2lds insts, 4 per wave
        const u16* gsrcA[4]; u16* ldstA[4];
#pragma unroll
        for (int t = 0; t < 4; ++t) {
            int idx = wid * 4 + t;
            int pan = idx >> 3, sub = idx & 7;
            gsrcA[t] = Wt + (size_t)(y * 128 + sub * 16 + lrow) * 768 + pan * 32 + lk;
            ldstA[t] = As + pan * 4096 + sub * 512;
        }
        // B convert setup: thread -> row = tid&63, kp = tid>>6 (16 k each)
        const int brow = tid & 63, kp = tid >> 6;
        const f32x4* gx = (const f32x4*)(x + (size_t)(j0 + brow) * 768 + kp * 16);
        u16* bdst = Bs + (kp >> 1) * 2048 + (brow >> 4) * 512 + (brow & 15) * 8;
        const int bo0 = (kp & 1) * 2 * 128, bo1 = bo0 + 128;

        f32x4 acc[4][2] = {};
        for (int kk = 0; kk < 12; ++kk) {
#pragma unroll
            for (int t = 0; t < 4; ++t) gl2lds16(gsrcA[t], ldstA[t]);
#pragma unroll
            for (int t = 0; t < 4; ++t) gsrcA[t] += 64;
            f32x4 a0 = gx[0], a1 = gx[1], a2 = gx[2], a3 = gx[3];
            gx += 16;
            u16x8 w0, w1;
#pragma unroll
            for (int j = 0; j < 4; ++j) {
                w0[j] = f2bf(a0[j]); w0[4 + j] = f2bf(a1[j]);
                w1[j] = f2bf(a2[j]); w1[4 + j] = f2bf(a3[j]);
            }
            *(u16x8*)(bdst + bo0) = w0;
            *(u16x8*)(bdst + bo1) = w1;
            __syncthreads();
#pragma unroll
            for (int pan = 0; pan < 2; ++pan) {
                u16x8 af[4], bq[2];
#pragma unroll
                for (int f = 0; f < 4; ++f)
                    af[f] = *(const u16x8*)(As + pan * 4096 + (wr * 4 + f) * 512 + lane * 8);
#pragma unroll
                for (int f = 0; f < 2; ++f)
                    bq[f] = *(const u16x8*)(Bs + pan * 2048 + (wc * 2 + f) * 512 + lane * 8);
#pragma unroll
                for (int fi = 0; fi < 4; ++fi)
#pragma unroll
                    for (int fj = 0; fj < 2; ++fj)
                        acc[fi][fj] = mfma16(af[fi], bq[fj], acc[fi][fj]);
            }
            __syncthreads();
        }
        // epilogue: per-wave repack 64(o-rows) x 32(m), stride 40 u16
        u16* Rw = (u16*)smem + wid * 2560;
#pragma unroll
        for (int fi = 0; fi < 4; ++fi)
#pragma unroll
            for (int fj = 0; fj < 2; ++fj)
#pragma unroll
                for (int r = 0; r < 4; ++r)
                    Rw[(fi * 16 + q * 4 + r) * 40 + fj * 16 + lrow] = f2bf(acc[fi][fj][r]);
        __syncthreads();
        const int k = y * 2 + wr;
        const int b = rt >> 3;
        const int m0 = (j0 & 511) + wc * 32;
#pragma unroll
        for (int p = 0; p < 4; ++p) {
            int row = p * 16 + (lane >> 2);          // o
            int cc = (lane & 3) * 8;
            u16x8 v = *(const u16x8*)(Rw + row * 40 + cc);
            *(u16x8*)(Z + (size_t)(b * 64 + row) * 2048 + k * 512 + m0 + cc) = v;
        }
    } else {
        // msq: 128x128 tile of M_s^2
        u16* St = (u16*)smem;                  // 2 panels x 16 KB
        int lb = bid - 512;
        int s = lb >> 4, rem = lb & 15;
        int i0 = (rem >> 2) * 128, j0 = (rem & 3) * 128;
        const u16* Ab = MallC_in + s * 1024;   // stride 2048
        const u16* Bb = MT + (size_t)s * 262144; // stride 512

        const u16* gsrc[8]; u16* ldst[8];
#pragma unroll
        for (int t = 0; t < 8; ++t) {
            int idx = wid * 8 + t;
            int pan = idx >> 4, q2 = idx & 15;
            if (q2 < 8) {
                gsrc[t] = Ab + (size_t)(i0 + q2 * 16 + lrow) * 2048 + pan * 32 + lk;
                ldst[t] = St + pan * 8192 + q2 * 512;
            } else {
                gsrc[t] = Bb + (size_t)(j0 + (q2 - 8) * 16 + lrow) * 512 + pan * 32 + lk;
                ldst[t] = St + pan * 8192 + 4096 + (q2 - 8) * 512;
            }
        }
        f32x4 acc[4][4] = {};
        for (int kk = 0; kk < 8; ++kk) {
#pragma unroll
            for (int t = 0; t < 8; ++t) gl2lds16(gsrc[t], ldst[t]);
#pragma unroll
            for (int t = 0; t < 8; ++t) gsrc[t] += 64;
            __syncthreads();
#pragma unroll
            for (int pan = 0; pan < 2; ++pan) {
                u16x8 af[4], bq[4];
#pragma unroll
                for (int f = 0; f < 4; ++f)
                    af[f] = *(const u16x8*)(St + pan * 8192 + (wr * 4 + f) * 512 + lane * 8);
#pragma unroll
                for (int f = 0; f < 4; ++f)
                    bq[f] = *(const u16x8*)(St + pan * 8192 + 4096 + (wc * 4 + f) * 512 + lane * 8);
#pragma unroll
                for (int fi = 0; fi < 4; ++fi)
#pragma unroll
                    for (int fj = 0; fj < 4; ++fj)
                        acc[fi][fj] = mfma16(af[fi], bq[fj], acc[fi][fj]);
            }
            __syncthreads();
        }
#pragma unroll
        for (int fi = 0; fi < 4; ++fi)
#pragma unroll
            for (int fj = 0; fj < 4; ++fj)
#pragma unroll
                for (int r = 0; r < 4; ++r) {
                    int n = i0 + wr * 64 + fi * 16 + q * 4 + r;
                    int c = j0 + wc * 64 + fj * 16 + lrow;
                    MallC_out[(size_t)n * 2048 + (2 * s + 1) * 512 + c] = f2bf(acc[fi][fj][r]);
                }
    }
}

// ---------------------------------------------------------------------------
// ysum: bid -> rt = bid&255 (64-row r-tile), ks = bid>>8 (k half).
// Yh[ks][r][o] = sum_{km in half} MallC[n][km] * Z[(b*64+o)][km]
// 64x64 tile, K=1024, BK=64. Waves 2x2 of 32x32.
// ---------------------------------------------------------------------------
__global__ __launch_bounds__(256) void ysum(
    const u16* __restrict__ MallC, const u16* __restrict__ Z,
    float* __restrict__ Yh)
{
    __shared__ __align__(16) u16 St[8192];     // A 2x4x512 | B 2x4x512
    u16* As = St; u16* Bs = St + 4096;
    const int tid = threadIdx.x, lane = tid & 63, wid = tid >> 6;
    const int wr = wid >> 1, wc = wid & 1;
    const int lrow = lane & 15, lk = (lane >> 4) * 8;
    const int bid = blockIdx.x;
    const int rt = bid & 255, ks = bid >> 8;
    const int r0 = rt * 64, b = rt >> 3, n0 = r0 & 511;
    const size_t km0 = (size_t)ks * 1024;

    const u16* gsrc[4]; u16* ldst[4];
#pragma unroll
    for (int t = 0; t < 4; ++t) {
        int idx = wid * 4 + t;
        int pan = idx >> 3, q2 = idx & 7;
        if (q2 < 4) {
            gsrc[t] = MallC + (size_t)(n0 + q2 * 16 + lrow) * 2048 + km0 + pan * 32 + lk;
            ldst[t] = As + pan * 2048 + q2 * 512;
        } else {
            int s2 = q2 - 4;
            gsrc[t] = Z + (size_t)(b * 64 + s2 * 16 + lrow) * 2048 + km0 + pan * 32 + lk;
            ldst[t] = Bs + pan * 2048 + s2 * 512;
        }
    }
    f32x4 acc[2][2] = {};
    for (int kk = 0; kk < 16; ++kk) {
#pragma unroll
        for (int t = 0; t < 4; ++t) gl2lds16(gsrc[t], ldst[t]);
#pragma unroll
        for (int t = 0; t < 4; ++t) gsrc[t] += 64;
        __syncthreads();
#pragma unroll
        for (int pan = 0; pan < 2; ++pan) {
            u16x8 af[2], bq[2];
#pragma unroll
            for (int f = 0; f < 2; ++f)
                af[f] = *(const u16x8*)(As + pan * 2048 + (wr * 2 + f) * 512 + lane * 8);
#pragma unroll
            for (int f = 0; f < 2; ++f)
                bq[f] = *(const u16x8*)(Bs + pan * 2048 + (wc * 2 + f) * 512 + lane * 8);
#pragma unroll
            for (int fi = 0; fi < 2; ++fi)
#pragma unroll
                for (int fj = 0; fj < 2; ++fj)
                    acc[fi][fj] = mfma16(af[fi], bq[fj], acc[fi][fj]);
        }
        __syncthreads();
    }
    const int q = lane >> 4;
    float* Yk = Yh + (size_t)ks * R_ * 64;
#pragma unroll
    for (int fi = 0; fi < 2; ++fi)
#pragma unroll
        for (int fj = 0; fj < 2; ++fj)
#pragma unroll
            for (int r = 0; r < 4; ++r) {
                int rr = r0 + wr * 32 + fi * 16 + q * 4 + r;
                int o  = wc * 32 + fj * 16 + lrow;
                Yk[(size_t)rr * 64 + o] = acc[fi][fj][r];
            }
}

// ---------------------------------------------------------------------------
// bn_part: grid 256, block j: rows j*64..+63, v = Yh0+Yh1, partial sum/sumsq.
// ---------------------------------------------------------------------------
__global__ __launch_bounds__(256) void bn_part(
    const float* __restrict__ Yh, float* __restrict__ part)
{
    const int blk = blockIdx.x, tid = threadIdx.x;
    const int o = tid & 63, g = tid >> 6;
    float s = 0.f, s2 = 0.f;
#pragma unroll
    for (int p = 0; p < 16; ++p) {
        int r = blk * 64 + p * 4 + g;
        size_t off = (size_t)r * 64 + o;
        float v = Yh[off] + Yh[(size_t)R_ * 64 + off];
        s += v; s2 += v * v;
    }
    __shared__ float ls[4][64], ls2[4][64];
    ls[g][o] = s; ls2[g][o] = s2;
    __syncthreads();
    if (tid < 64) {
        float t = 0.f, t2 = 0.f;
#pragma unroll
        for (int g2 = 0; g2 < 4; ++g2) { t += ls[g2][tid]; t2 += ls2[g2][tid]; }
        part[blk * 128 + tid]      = t;
        part[blk * 128 + 64 + tid] = t2;
    }
}

// bn_final: stats[o] = scale, stats[64+o] = shift
__global__ __launch_bounds__(256) void bn_final(
    const float* __restrict__ part, const float* __restrict__ gamma,
    const float* __restrict__ beta, float* __restrict__ stats)
{
    const int tid = threadIdx.x;
    const int c = tid & 63, g = tid >> 6;
    float s = 0.f, s2 = 0.f;
    for (int b = g; b < 256; b += 4) {
        s  += part[b * 128 + c];
        s2 += part[b * 128 + 64 + c];
    }
    __shared__ float ls[4][64], ls2[4][64];
    ls[g][c] = s; ls2[g][c] = s2;
    __syncthreads();
    if (tid < 64) {
        float t = 0.f, t2 = 0.f;
#pragma unroll
        for (int g2 = 0; g2 < 4; ++g2) { t += ls[g2][tid]; t2 += ls2[g2][tid]; }
        float mean = t * (1.0f / R_);
        float var  = t2 * (1.0f / R_) - mean * mean;
        float a = rsqrtf(var + 1e-5f) * gamma[tid];
        stats[tid]      = a;
        stats[64 + tid] = beta[tid] - mean * a;
    }
}

// ---------------------------------------------------------------------------
// bn_out: out[r][o] = sum_c relu(v[r][c]*a[c]+sh[c]) * w2[o][c] + b2[o]
// v = Yh0+Yh1. grid 256 blocks of 64 rows.
// ---------------------------------------------------------------------------
__global__ __launch_bounds__(256) void bn_out(
    const float* __restrict__ Yh, const float* __restrict__ stats,
    const float* __restrict__ w2, const float* __restrict__ b2,
    float* __restrict__ out)
{
    __shared__ float ys[64 * 68];
    __shared__ float w2s[64 * 65];
    __shared__ float sa[64], sh[64];
    const int tid = threadIdx.x;
    const int r0 = blockIdx.x * 64;
#pragma unroll
    for (int i = 0; i < 16; ++i) {
        int idx = tid + i * 256;
        w2s[(idx >> 6) * 65 + (idx & 63)] = w2[idx];
    }
    if (tid < 64) { sa[tid] = stats[tid]; sh[tid] = stats[64 + tid]; }
    __syncthreads();
    const int o = tid & 63, g = tid >> 6;
    {
        float a = sa[o], b = sh[o];
#pragma unroll
        for (int p = 0; p < 16; ++p) {
            int rl = p * 4 + g;
            size_t off = (size_t)(r0 + rl) * 64 + o;
            float v = Yh[off] + Yh[(size_t)R_ * 64 + off];
            ys[o * 68 + rl] = fmaxf(fmaf(v, a, b), 0.f);
        }
    }
    __syncthreads();
    float acc[16];
    float bb = b2[o];
#pragma unroll
    for (int j = 0; j < 16; ++j) acc[j] = bb;
    for (int c = 0; c < 64; ++c) {
        float wv = w2s[o * 65 + c];
        const float* yr = ys + c * 68 + g * 16;
        f32x4 y0 = *(const f32x4*)(yr);
        f32x4 y1 = *(const f32x4*)(yr + 4);
        f32x4 y2 = *(const f32x4*)(yr + 8);
        f32x4 y3 = *(const f32x4*)(yr + 12);
#pragma unroll
        for (int j = 0; j < 4; ++j) {
            acc[j]      = fmaf(wv, y0[j], acc[j]);
            acc[4 + j]  = fmaf(wv, y1[j], acc[4 + j]);
            acc[8 + j]  = fmaf(wv, y2[j], acc[8 + j]);
            acc[12 + j] = fmaf(wv, y3[j], acc[12 + j]);
        }
    }
#pragma unroll
    for (int j = 0; j < 16; ++j)
        out[(size_t)(r0 + g * 16 + j) * OUT_ + o] = acc[j];
}

// ---------------------------------------------------------------------------
extern "C" void kernel_launch(void* const* d_in, const int* in_sizes, int n_in,
                              void* d_out, int out_size, void* d_ws, size_t ws_size,
                              hipStream_t stream)
{
    const float* x       = (const float*)d_in[0];
    const float* support = (const float*)d_in[1];
    const float* weight  = (const float*)d_in[2];
    const float* eps     = (const float*)d_in[3];
    const float* gamma   = (const float*)d_in[4];
    const float* beta    = (const float*)d_in[5];
    const float* w2      = (const float*)d_in[6];
    const float* b2      = (const float*)d_in[7];
    float* out = (float*)d_out;

    char* ws = (char*)d_ws;
    u16*   MallC = (u16*)(ws);                      //  2,097,152  [512][2048]
    u16*   MT    = (u16*)(ws + 2097152);            //  1,048,576
    u16*   Wt    = (u16*)(ws + 3145728);            //    393,216  [256][768]
    u16*   Z     = (u16*)(ws + 3538944);            //  8,388,608  [2048][2048]
    float* Yh    = (float*)(ws + 11927552);         //  8,388,608  (2 halves)
    float* part  = (float*)(ws + 20316160);         //    131,072
    float* stats = (float*)(ws + 20447232);         //        512

    prep2     <<<1280, 256, 0, stream>>>(support, weight, eps, MallC, MT, Wt);
    zgemm_fused<<<544, 256, 0, stream>>>(Wt, x, MallC, MT, Z, MallC);
    ysum      <<<512,  256, 0, stream>>>(MallC, Z, Yh);
    bn_part   <<<256,  256, 0, stream>>>(Yh, part);
    bn_final  <<<1,    256, 0, stream>>>(part, gamma, beta, stats);
    bn_out    <<<256,  256, 0, stream>>>(Yh, stats, w2, b2, out);
}